// Round 17
// baseline (26.919 us; speedup 1.0000x reference)
//
#include <hip/hip_runtime.h>
#include <math.h>

typedef float  f32x4  __attribute__((ext_vector_type(4)));
typedef short  bf16x8 __attribute__((ext_vector_type(8)));

namespace {
constexpr int R_RUNS  = 4096;
constexpr int T_STEPS = 2048;
constexpr int NKS     = 3;   // three K=32 MFMA steps (K=96, 72 used)
constexpr size_t PA_ELEMS = (size_t)(R_RUNS / 16) * NKS * 4 * 16 * 8;  // 393216 ushort
}

__device__ __forceinline__ float sigmoidf_(float x) { return 1.0f / (1.0f + expf(-x)); }

__device__ __forceinline__ unsigned short f2bf(float f) {
    unsigned u = __float_as_uint(f);
    unsigned r = (u + 0x7FFFu + ((u >> 16) & 1u)) >> 16;
    return (unsigned short)r;
}
__device__ __forceinline__ float bf2f(unsigned short h) {
    return __uint_as_float(((unsigned)h) << 16);
}
__device__ __forceinline__ float powg(float gh, int e) {   // gh^e, e in [0,63]
    float w = 1.f, p = gh;
    #pragma unroll
    for (int i = 0; i < 6; ++i) { w *= ((e >> i) & 1) ? p : 1.f; p *= p; }
    return w;
}

// ---------------------------------------------------------------------------
// K1 (24 blocks) — R13-verified. Launched TWICE this round as a timing probe
// (idempotent: pure function of inputs -> Pa/Qb). dur - 20.4us == K1 cost.
//   blocks 0-7  (32 waves): W-scan + Qb pack (t fragments).
//   blocks 8-23 (64 waves): Pa pack (r fragments), independent of W.
// ---------------------------------------------------------------------------
extern "C" __global__ __launch_bounds__(256)
void dlm_k1_pack(const float* __restrict__ Xt, const float* __restrict__ Zt,
                 const float* __restrict__ G, const float* __restrict__ eta,
                 const float* __restrict__ zeta, const float* __restrict__ gamma,
                 unsigned short* __restrict__ Pa, unsigned short* __restrict__ Qb)
{
    const int tid  = threadIdx.x;
    const int wid  = tid >> 6;
    const int lane = tid & 63;

    if (blockIdx.x >= 8) {
        const int pw = (blockIdx.x - 8) * 4 + wid;   // 0..63
        const int r  = pw * 64 + lane;
        const float4 e0 = *reinterpret_cast<const float4*>(eta   + (size_t)r * 8);
        const float4 e1 = *reinterpret_cast<const float4*>(eta   + (size_t)r * 8 + 4);
        const float4 c0 = *reinterpret_cast<const float4*>(zeta  + (size_t)r * 8);
        const float4 c1 = *reinterpret_cast<const float4*>(zeta  + (size_t)r * 8 + 4);
        const float4 m0 = *reinterpret_cast<const float4*>(gamma + (size_t)r * 8);
        const float4 m1 = *reinterpret_cast<const float4*>(gamma + (size_t)r * 8 + 4);
        const float pr[24] = {e0.x, e0.y, e0.z, e0.w, e1.x, e1.y, e1.z, e1.w,
                              c0.x, c0.y, c0.z, c0.w, c1.x, c1.y, c1.z, c1.w,
                              m0.x, m0.y, m0.z, m0.w, m1.x, m1.y, m1.z, m1.w};
        const int rt = r >> 4, rw = r & 15;
        #pragma unroll
        for (int s = 0; s < NKS; ++s) {
            #pragma unroll
            for (int ko = 0; ko < 4; ++ko) {
                union { unsigned short u[8]; uint4 v; } pk;
                #pragma unroll
                for (int i = 0; i < 8; ++i) {
                    const int k = s * 32 + ko * 8 + i;
                    unsigned short o;
                    if (k < 24)      o = f2bf(pr[k]);
                    else if (k < 48) o = f2bf(pr[k - 24]);
                    else if (k < 72) { const unsigned short h = f2bf(pr[k - 48]);
                                       o = f2bf(pr[k - 48] - bf2f(h)); }
                    else             o = 0;
                    pk.u[i] = o;
                }
                *reinterpret_cast<uint4*>(Pa + ((size_t)((rt * NKS + s) * 4 + ko) * 16 + rw) * 8) = pk.v;
            }
        }
        return;
    }

    const int wv = blockIdx.x * 4 + wid;   // 0..31
    const int t  = wv * 64 + lane;

    const float gh = sigmoidf_(G[0]);
    float gh64 = gh;
    #pragma unroll
    for (int i = 0; i < 6; ++i) gh64 *= gh64;

    const float4 za = *reinterpret_cast<const float4*>(Zt + (size_t)t * 8);
    const float4 zb = *reinterpret_cast<const float4*>(Zt + (size_t)t * 8 + 4);
    const float4 xa = *reinterpret_cast<const float4*>(Xt + (size_t)t * 8);
    const float4 xb = *reinterpret_cast<const float4*>(Xt + (size_t)t * 8 + 4);

    float acc[8] = {0.f, 0.f, 0.f, 0.f, 0.f, 0.f, 0.f, 0.f};
    for (int m = 0; m < wv; ++m) {
        const float* __restrict__ zp = Zt + (size_t)(m * 64 + lane) * 8;
        const float4 pa = *reinterpret_cast<const float4*>(zp);
        const float4 pb = *reinterpret_cast<const float4*>(zp + 4);
        acc[0] = fmaf(gh64, acc[0], pa.x);
        acc[1] = fmaf(gh64, acc[1], pa.y);
        acc[2] = fmaf(gh64, acc[2], pa.z);
        acc[3] = fmaf(gh64, acc[3], pa.w);
        acc[4] = fmaf(gh64, acc[4], pb.x);
        acc[5] = fmaf(gh64, acc[5], pb.y);
        acc[6] = fmaf(gh64, acc[6], pb.z);
        acc[7] = fmaf(gh64, acc[7], pb.w);
    }
    const float wl = powg(gh, 63 - lane);
    #pragma unroll
    for (int i = 0; i < 8; ++i) acc[i] *= wl;
    #pragma unroll
    for (int d = 1; d < 64; d <<= 1) {
        #pragma unroll
        for (int i = 0; i < 8; ++i)
            acc[i] += __shfl_xor(acc[i], d, 64);
    }

    float I[8] = {za.x, za.y, za.z, za.w, zb.x, zb.y, zb.z, zb.w};
    float p = gh;
    #pragma unroll
    for (int d = 1; d < 64; d <<= 1) {
        #pragma unroll
        for (int i = 0; i < 8; ++i) {
            const float up = __shfl_up(I[i], (unsigned)d, 64);
            if (lane >= d) I[i] = fmaf(p, up, I[i]);
        }
        p *= p;
    }

    const float wj = powg(gh, lane);
    float Wt[8];
    #pragma unroll
    for (int i = 0; i < 8; ++i) {
        const float L = __shfl_up(I[i], 1u, 64);
        Wt[i] = fmaf(wj, acc[i], (lane == 0) ? 0.0f : L);
    }

    const float q[24] = {xa.x, xa.y, xa.z, xa.w, xb.x, xb.y, xb.z, xb.w,
                         za.x, za.y, za.z, za.w, zb.x, zb.y, zb.z, zb.w,
                         Wt[0], Wt[1], Wt[2], Wt[3], Wt[4], Wt[5], Wt[6], Wt[7]};
    const int tt = t >> 4, c = t & 15;
    #pragma unroll
    for (int s = 0; s < NKS; ++s) {
        #pragma unroll
        for (int ko = 0; ko < 4; ++ko) {
            union { unsigned short u[8]; uint4 v; } pk;
            #pragma unroll
            for (int i = 0; i < 8; ++i) {
                const int k = s * 32 + ko * 8 + i;
                unsigned short o;
                if (k < 24)      o = f2bf(q[k]);
                else if (k < 48) { const unsigned short h = f2bf(q[k - 24]);
                                   o = f2bf(q[k - 24] - bf2f(h)); }
                else if (k < 72) o = f2bf(q[k - 48]);
                else             o = 0;
                pk.u[i] = o;
            }
            *reinterpret_cast<uint4*>(Qb + ((size_t)((tt * NKS + s) * 4 + ko) * 16 + c) * 8) = pk.v;
        }
    }
}

// ---------------------------------------------------------------------------
// KB — exact R13 version (best measured: 7.8us). wave -> 32x32 output tile
// (2x2 of 16x16 MFMA), 12 dwordx4 frag loads + 12 MFMA + 16 NT dword stores.
// Fallback (wave's G slice not all == G[0]): exact serial replay from t=0.
// ---------------------------------------------------------------------------
extern "C" __global__ __launch_bounds__(256)
void dlm_kb_mfma(const float* __restrict__ Xt, const float* __restrict__ Zt,
                 const float* __restrict__ G, const float* __restrict__ eta,
                 const float* __restrict__ zeta, const float* __restrict__ gamma,
                 const unsigned short* __restrict__ Pa,
                 const unsigned short* __restrict__ Qb,
                 float* __restrict__ out)
{
    const int tid  = threadIdx.x;
    const int wid  = tid >> 6;
    const int lane = tid & 63;
    const int w    = blockIdx.x * 4 + wid;    // 0..8191
    const int rt0  = (w & 127) * 2;
    const int tt0  = (w >> 7) * 2;
    const int r0   = rt0 * 16;
    const int t0   = tt0 * 16;

    const float G0 = G[0];
    const float gv = G[r0 + (lane & 31)];
    const bool uni = (__ballot(gv == G0) == ~0ull);

    if (uni) {
        const int ko = lane >> 4;
        const int rc = lane & 15;

        bf16x8 af[2][NKS], bfr[2][NKS];
        #pragma unroll
        for (int i = 0; i < 2; ++i)
            #pragma unroll
            for (int s = 0; s < NKS; ++s) {
                af[i][s] = *reinterpret_cast<const bf16x8*>(
                    Pa + ((size_t)(((rt0 + i) * NKS + s) * 4 + ko) * 16 + rc) * 8);
                bfr[i][s] = *reinterpret_cast<const bf16x8*>(
                    Qb + ((size_t)(((tt0 + i) * NKS + s) * 4 + ko) * 16 + rc) * 8);
            }

        f32x4 accv[2][2];
        #pragma unroll
        for (int i = 0; i < 2; ++i)
            #pragma unroll
            for (int j = 0; j < 2; ++j)
                accv[i][j] = (f32x4){0.f, 0.f, 0.f, 0.f};

        #pragma unroll
        for (int s = 0; s < NKS; ++s)
            #pragma unroll
            for (int i = 0; i < 2; ++i)
                #pragma unroll
                for (int j = 0; j < 2; ++j)
                    accv[i][j] = __builtin_amdgcn_mfma_f32_16x16x32_bf16(
                        af[i][s], bfr[j][s], accv[i][j], 0, 0, 0);

        const int orow = (lane >> 4) * 4;
        const int ocol = lane & 15;
        #pragma unroll
        for (int i = 0; i < 2; ++i)
            #pragma unroll
            for (int j = 0; j < 2; ++j)
                #pragma unroll
                for (int qv = 0; qv < 4; ++qv)
                    __builtin_nontemporal_store(
                        accv[i][j][qv],
                        &out[(size_t)(r0 + 16 * i + orow + qv) * T_STEPS + t0 + 16 * j + ocol]);
    } else {
        const int t = t0 + (lane & 31);
        const float4 fxa = *reinterpret_cast<const float4*>(Xt + (size_t)t * 8);
        const float4 fxb = *reinterpret_cast<const float4*>(Xt + (size_t)t * 8 + 4);
        const float4 fza = *reinterpret_cast<const float4*>(Zt + (size_t)t * 8);
        const float4 fzb = *reinterpret_cast<const float4*>(Zt + (size_t)t * 8 + 4);
        for (int rr = 0; rr < 32; ++rr) {
            const int r = r0 + rr;
            const float ghr = sigmoidf_(G[r]);
            const float* __restrict__ gc = gamma + (size_t)r * 8;
            const float* __restrict__ e  = eta   + (size_t)r * 8;
            const float* __restrict__ zc = zeta  + (size_t)r * 8;
            float th = 0.0f, mine = 0.0f;
            for (int s2 = 1; s2 <= t0 + 31; ++s2) {
                const float* __restrict__ zr = Zt + (size_t)(s2 - 1) * 8;
                float b = zr[0] * gc[0];
                #pragma unroll
                for (int qq = 1; qq < 8; ++qq) b = fmaf(zr[qq], gc[qq], b);
                th = fmaf(ghr, th, b);
                mine = (s2 == t) ? th : mine;
            }
            float s = mine;
            s = fmaf(fxa.x, e[0], s);  s = fmaf(fxa.y, e[1], s);
            s = fmaf(fxa.z, e[2], s);  s = fmaf(fxa.w, e[3], s);
            s = fmaf(fxb.x, e[4], s);  s = fmaf(fxb.y, e[5], s);
            s = fmaf(fxb.z, e[6], s);  s = fmaf(fxb.w, e[7], s);
            s = fmaf(fza.x, zc[0], s); s = fmaf(fza.y, zc[1], s);
            s = fmaf(fza.z, zc[2], s); s = fmaf(fza.w, zc[3], s);
            s = fmaf(fzb.x, zc[4], s); s = fmaf(fzb.y, zc[5], s);
            s = fmaf(fzb.z, zc[6], s); s = fmaf(fzb.w, zc[7], s);
            if (lane < 32) out[(size_t)r * T_STEPS + t] = s;
        }
    }
}

// ---------------------------------------------------------------------------
extern "C" void kernel_launch(void* const* d_in, const int* in_sizes, int n_in,
                              void* d_out, int out_size, void* d_ws, size_t ws_size,
                              hipStream_t stream)
{
    const float* Xt    = (const float*)d_in[0];
    const float* Zt    = (const float*)d_in[1];
    const float* G     = (const float*)d_in[2];
    const float* eta   = (const float*)d_in[3];
    const float* zeta  = (const float*)d_in[4];
    const float* gamma = (const float*)d_in[5];
    float* out = (float*)d_out;

    unsigned short* Pa = (unsigned short*)d_ws;
    unsigned short* Qb = Pa + PA_ELEMS;

    const dim3 blk(256);
    // Probe: K1 launched twice (idempotent). dur - 20.4us isolates K1's cost.
    dlm_k1_pack<<<dim3(24),   blk, 0, stream>>>(Xt, Zt, G, eta, zeta, gamma, Pa, Qb);
    dlm_k1_pack<<<dim3(24),   blk, 0, stream>>>(Xt, Zt, G, eta, zeta, gamma, Pa, Qb);
    dlm_kb_mfma<<<dim3(2048), blk, 0, stream>>>(Xt, Zt, G, eta, zeta, gamma, Pa, Qb, out);
}

// Round 18
// 19.084 us; speedup vs baseline: 1.4106x; 1.4106x over previous
//
#include <hip/hip_runtime.h>
#include <math.h>

typedef float  f32x4  __attribute__((ext_vector_type(4)));
typedef short  bf16x8 __attribute__((ext_vector_type(8)));

namespace {
constexpr int R_RUNS  = 4096;
constexpr int T_STEPS = 2048;
constexpr int NKS     = 3;   // three K=32 MFMA steps (K=96, 72 used)
constexpr size_t PA_ELEMS = (size_t)(R_RUNS / 16) * NKS * 4 * 16 * 8;  // 393216 ushort
}

__device__ __forceinline__ float sigmoidf_(float x) { return 1.0f / (1.0f + expf(-x)); }

__device__ __forceinline__ unsigned short f2bf(float f) {
    unsigned u = __float_as_uint(f);
    unsigned r = (u + 0x7FFFu + ((u >> 16) & 1u)) >> 16;
    return (unsigned short)r;
}
__device__ __forceinline__ float bf2f(unsigned short h) {
    return __uint_as_float(((unsigned)h) << 16);
}
__device__ __forceinline__ float powg(float gh, int e) {   // gh^e, e in [0,63]
    float w = 1.f, p = gh;
    #pragma unroll
    for (int i = 0; i < 6; ++i) { w *= ((e >> i) & 1) ? p : 1.f; p *= p; }
    return w;
}

// ---------------------------------------------------------------------------
// K1 (24 blocks):
//   blocks 0-7  (32 waves): W-scan + Qb pack. W-prefix now BATCHED: 8
//     independent row loads in flight per group, then 8 predicated Horner
//     FMAs (R17 probe showed the serial load->fma chain cost ~4.5us).
//   blocks 8-23 (64 waves): Pa pack (r fragments), independent of W.
// ---------------------------------------------------------------------------
extern "C" __global__ __launch_bounds__(256)
void dlm_k1_pack(const float* __restrict__ Xt, const float* __restrict__ Zt,
                 const float* __restrict__ G, const float* __restrict__ eta,
                 const float* __restrict__ zeta, const float* __restrict__ gamma,
                 unsigned short* __restrict__ Pa, unsigned short* __restrict__ Qb)
{
    const int tid  = threadIdx.x;
    const int wid  = tid >> 6;
    const int lane = tid & 63;

    if (blockIdx.x >= 8) {
        const int pw = (blockIdx.x - 8) * 4 + wid;   // 0..63
        const int r  = pw * 64 + lane;
        const float4 e0 = *reinterpret_cast<const float4*>(eta   + (size_t)r * 8);
        const float4 e1 = *reinterpret_cast<const float4*>(eta   + (size_t)r * 8 + 4);
        const float4 c0 = *reinterpret_cast<const float4*>(zeta  + (size_t)r * 8);
        const float4 c1 = *reinterpret_cast<const float4*>(zeta  + (size_t)r * 8 + 4);
        const float4 m0 = *reinterpret_cast<const float4*>(gamma + (size_t)r * 8);
        const float4 m1 = *reinterpret_cast<const float4*>(gamma + (size_t)r * 8 + 4);
        const float pr[24] = {e0.x, e0.y, e0.z, e0.w, e1.x, e1.y, e1.z, e1.w,
                              c0.x, c0.y, c0.z, c0.w, c1.x, c1.y, c1.z, c1.w,
                              m0.x, m0.y, m0.z, m0.w, m1.x, m1.y, m1.z, m1.w};
        const int rt = r >> 4, rw = r & 15;
        #pragma unroll
        for (int s = 0; s < NKS; ++s) {
            #pragma unroll
            for (int ko = 0; ko < 4; ++ko) {
                union { unsigned short u[8]; uint4 v; } pk;
                #pragma unroll
                for (int i = 0; i < 8; ++i) {
                    const int k = s * 32 + ko * 8 + i;
                    unsigned short o;
                    if (k < 24)      o = f2bf(pr[k]);
                    else if (k < 48) o = f2bf(pr[k - 24]);
                    else if (k < 72) { const unsigned short h = f2bf(pr[k - 48]);
                                       o = f2bf(pr[k - 48] - bf2f(h)); }
                    else             o = 0;
                    pk.u[i] = o;
                }
                *reinterpret_cast<uint4*>(Pa + ((size_t)((rt * NKS + s) * 4 + ko) * 16 + rw) * 8) = pk.v;
            }
        }
        return;
    }

    const int wv = blockIdx.x * 4 + wid;   // 0..31
    const int t  = wv * 64 + lane;

    const float gh = sigmoidf_(G[0]);
    float gh64 = gh;
    #pragma unroll
    for (int i = 0; i < 6; ++i) gh64 *= gh64;

    const float4 za = *reinterpret_cast<const float4*>(Zt + (size_t)t * 8);
    const float4 zb = *reinterpret_cast<const float4*>(Zt + (size_t)t * 8 + 4);
    const float4 xa = *reinterpret_cast<const float4*>(Xt + (size_t)t * 8);
    const float4 xb = *reinterpret_cast<const float4*>(Xt + (size_t)t * 8 + 4);

    // ---- W prefix, batched-8: issue 8 independent row loads, then 8
    //      predicated Horner steps (acc = act ? gh64*acc + row : acc).
    float acc[8] = {0.f, 0.f, 0.f, 0.f, 0.f, 0.f, 0.f, 0.f};
    #pragma unroll
    for (int base = 0; base < 32; base += 8) {
        if (base < wv) {                          // wave-uniform guard
            float4 pa[8], pb[8];
            #pragma unroll
            for (int i = 0; i < 8; ++i) {
                const int mm = (base + i < wv) ? (base + i) : (wv - 1);  // clamped, in-bounds
                const float* __restrict__ zp = Zt + (size_t)(mm * 64 + lane) * 8;
                pa[i] = *reinterpret_cast<const float4*>(zp);
                pb[i] = *reinterpret_cast<const float4*>(zp + 4);
            }
            #pragma unroll
            for (int i = 0; i < 8; ++i) {
                const bool act = (base + i) < wv;
                const float m = act ? gh64 : 1.0f;
                acc[0] = fmaf(m, acc[0], act ? pa[i].x : 0.0f);
                acc[1] = fmaf(m, acc[1], act ? pa[i].y : 0.0f);
                acc[2] = fmaf(m, acc[2], act ? pa[i].z : 0.0f);
                acc[3] = fmaf(m, acc[3], act ? pa[i].w : 0.0f);
                acc[4] = fmaf(m, acc[4], act ? pb[i].x : 0.0f);
                acc[5] = fmaf(m, acc[5], act ? pb[i].y : 0.0f);
                acc[6] = fmaf(m, acc[6], act ? pb[i].z : 0.0f);
                acc[7] = fmaf(m, acc[7], act ? pb[i].w : 0.0f);
            }
        }
    }
    const float wl = powg(gh, 63 - lane);
    #pragma unroll
    for (int i = 0; i < 8; ++i) acc[i] *= wl;
    #pragma unroll
    for (int d = 1; d < 64; d <<= 1) {
        #pragma unroll
        for (int i = 0; i < 8; ++i)
            acc[i] += __shfl_xor(acc[i], d, 64);
    }

    float I[8] = {za.x, za.y, za.z, za.w, zb.x, zb.y, zb.z, zb.w};
    float p = gh;
    #pragma unroll
    for (int d = 1; d < 64; d <<= 1) {
        #pragma unroll
        for (int i = 0; i < 8; ++i) {
            const float up = __shfl_up(I[i], (unsigned)d, 64);
            if (lane >= d) I[i] = fmaf(p, up, I[i]);
        }
        p *= p;
    }

    const float wj = powg(gh, lane);
    float Wt[8];
    #pragma unroll
    for (int i = 0; i < 8; ++i) {
        const float L = __shfl_up(I[i], 1u, 64);
        Wt[i] = fmaf(wj, acc[i], (lane == 0) ? 0.0f : L);
    }

    const float q[24] = {xa.x, xa.y, xa.z, xa.w, xb.x, xb.y, xb.z, xb.w,
                         za.x, za.y, za.z, za.w, zb.x, zb.y, zb.z, zb.w,
                         Wt[0], Wt[1], Wt[2], Wt[3], Wt[4], Wt[5], Wt[6], Wt[7]};
    const int tt = t >> 4, c = t & 15;
    #pragma unroll
    for (int s = 0; s < NKS; ++s) {
        #pragma unroll
        for (int ko = 0; ko < 4; ++ko) {
            union { unsigned short u[8]; uint4 v; } pk;
            #pragma unroll
            for (int i = 0; i < 8; ++i) {
                const int k = s * 32 + ko * 8 + i;
                unsigned short o;
                if (k < 24)      o = f2bf(q[k]);
                else if (k < 48) { const unsigned short h = f2bf(q[k - 24]);
                                   o = f2bf(q[k - 24] - bf2f(h)); }
                else if (k < 72) o = f2bf(q[k - 48]);
                else             o = 0;
                pk.u[i] = o;
            }
            *reinterpret_cast<uint4*>(Qb + ((size_t)((tt * NKS + s) * 4 + ko) * 16 + c) * 8) = pk.v;
        }
    }
}

// ---------------------------------------------------------------------------
// KB — exact R13 version (best measured: 7.8us). wave -> 32x32 output tile
// (2x2 of 16x16 MFMA), 12 dwordx4 frag loads + 12 MFMA + 16 NT dword stores.
// Fallback (wave's G slice not all == G[0]): exact serial replay from t=0.
// ---------------------------------------------------------------------------
extern "C" __global__ __launch_bounds__(256)
void dlm_kb_mfma(const float* __restrict__ Xt, const float* __restrict__ Zt,
                 const float* __restrict__ G, const float* __restrict__ eta,
                 const float* __restrict__ zeta, const float* __restrict__ gamma,
                 const unsigned short* __restrict__ Pa,
                 const unsigned short* __restrict__ Qb,
                 float* __restrict__ out)
{
    const int tid  = threadIdx.x;
    const int wid  = tid >> 6;
    const int lane = tid & 63;
    const int w    = blockIdx.x * 4 + wid;    // 0..8191
    const int rt0  = (w & 127) * 2;
    const int tt0  = (w >> 7) * 2;
    const int r0   = rt0 * 16;
    const int t0   = tt0 * 16;

    const float G0 = G[0];
    const float gv = G[r0 + (lane & 31)];
    const bool uni = (__ballot(gv == G0) == ~0ull);

    if (uni) {
        const int ko = lane >> 4;
        const int rc = lane & 15;

        bf16x8 af[2][NKS], bfr[2][NKS];
        #pragma unroll
        for (int i = 0; i < 2; ++i)
            #pragma unroll
            for (int s = 0; s < NKS; ++s) {
                af[i][s] = *reinterpret_cast<const bf16x8*>(
                    Pa + ((size_t)(((rt0 + i) * NKS + s) * 4 + ko) * 16 + rc) * 8);
                bfr[i][s] = *reinterpret_cast<const bf16x8*>(
                    Qb + ((size_t)(((tt0 + i) * NKS + s) * 4 + ko) * 16 + rc) * 8);
            }

        f32x4 accv[2][2];
        #pragma unroll
        for (int i = 0; i < 2; ++i)
            #pragma unroll
            for (int j = 0; j < 2; ++j)
                accv[i][j] = (f32x4){0.f, 0.f, 0.f, 0.f};

        #pragma unroll
        for (int s = 0; s < NKS; ++s)
            #pragma unroll
            for (int i = 0; i < 2; ++i)
                #pragma unroll
                for (int j = 0; j < 2; ++j)
                    accv[i][j] = __builtin_amdgcn_mfma_f32_16x16x32_bf16(
                        af[i][s], bfr[j][s], accv[i][j], 0, 0, 0);

        const int orow = (lane >> 4) * 4;
        const int ocol = lane & 15;
        #pragma unroll
        for (int i = 0; i < 2; ++i)
            #pragma unroll
            for (int j = 0; j < 2; ++j)
                #pragma unroll
                for (int qv = 0; qv < 4; ++qv)
                    __builtin_nontemporal_store(
                        accv[i][j][qv],
                        &out[(size_t)(r0 + 16 * i + orow + qv) * T_STEPS + t0 + 16 * j + ocol]);
    } else {
        const int t = t0 + (lane & 31);
        const float4 fxa = *reinterpret_cast<const float4*>(Xt + (size_t)t * 8);
        const float4 fxb = *reinterpret_cast<const float4*>(Xt + (size_t)t * 8 + 4);
        const float4 fza = *reinterpret_cast<const float4*>(Zt + (size_t)t * 8);
        const float4 fzb = *reinterpret_cast<const float4*>(Zt + (size_t)t * 8 + 4);
        for (int rr = 0; rr < 32; ++rr) {
            const int r = r0 + rr;
            const float ghr = sigmoidf_(G[r]);
            const float* __restrict__ gc = gamma + (size_t)r * 8;
            const float* __restrict__ e  = eta   + (size_t)r * 8;
            const float* __restrict__ zc = zeta  + (size_t)r * 8;
            float th = 0.0f, mine = 0.0f;
            for (int s2 = 1; s2 <= t0 + 31; ++s2) {
                const float* __restrict__ zr = Zt + (size_t)(s2 - 1) * 8;
                float b = zr[0] * gc[0];
                #pragma unroll
                for (int qq = 1; qq < 8; ++qq) b = fmaf(zr[qq], gc[qq], b);
                th = fmaf(ghr, th, b);
                mine = (s2 == t) ? th : mine;
            }
            float s = mine;
            s = fmaf(fxa.x, e[0], s);  s = fmaf(fxa.y, e[1], s);
            s = fmaf(fxa.z, e[2], s);  s = fmaf(fxa.w, e[3], s);
            s = fmaf(fxb.x, e[4], s);  s = fmaf(fxb.y, e[5], s);
            s = fmaf(fxb.z, e[6], s);  s = fmaf(fxb.w, e[7], s);
            s = fmaf(fza.x, zc[0], s); s = fmaf(fza.y, zc[1], s);
            s = fmaf(fza.z, zc[2], s); s = fmaf(fza.w, zc[3], s);
            s = fmaf(fzb.x, zc[4], s); s = fmaf(fzb.y, zc[5], s);
            s = fmaf(fzb.z, zc[6], s); s = fmaf(fzb.w, zc[7], s);
            if (lane < 32) out[(size_t)r * T_STEPS + t] = s;
        }
    }
}

// ---------------------------------------------------------------------------
extern "C" void kernel_launch(void* const* d_in, const int* in_sizes, int n_in,
                              void* d_out, int out_size, void* d_ws, size_t ws_size,
                              hipStream_t stream)
{
    const float* Xt    = (const float*)d_in[0];
    const float* Zt    = (const float*)d_in[1];
    const float* G     = (const float*)d_in[2];
    const float* eta   = (const float*)d_in[3];
    const float* zeta  = (const float*)d_in[4];
    const float* gamma = (const float*)d_in[5];
    float* out = (float*)d_out;

    unsigned short* Pa = (unsigned short*)d_ws;
    unsigned short* Qb = Pa + PA_ELEMS;

    const dim3 blk(256);
    dlm_k1_pack<<<dim3(24),   blk, 0, stream>>>(Xt, Zt, G, eta, zeta, gamma, Pa, Qb);
    dlm_kb_mfma<<<dim3(2048), blk, 0, stream>>>(Xt, Zt, G, eta, zeta, gamma, Pa, Qb, out);
}

// Round 19
// 18.677 us; speedup vs baseline: 1.4413x; 1.0218x over previous
//
#include <hip/hip_runtime.h>
#include <math.h>

typedef float  f32x4  __attribute__((ext_vector_type(4)));
typedef short  bf16x8 __attribute__((ext_vector_type(8)));

namespace {
constexpr int R_RUNS  = 4096;
constexpr int T_STEPS = 2048;
constexpr int NKS     = 3;   // three K=32 MFMA steps (K=96, 72 used)
constexpr size_t PA_ELEMS = (size_t)(R_RUNS / 16) * NKS * 4 * 16 * 8;  // 393216 ushort
}

__device__ __forceinline__ float sigmoidf_(float x) { return 1.0f / (1.0f + expf(-x)); }

__device__ __forceinline__ unsigned short f2bf(float f) {
    unsigned u = __float_as_uint(f);
    unsigned r = (u + 0x7FFFu + ((u >> 16) & 1u)) >> 16;
    return (unsigned short)r;
}
__device__ __forceinline__ float bf2f(unsigned short h) {
    return __uint_as_float(((unsigned)h) << 16);
}
__device__ __forceinline__ float powg(float gh, int e) {   // gh^e, e in [0,63]
    float w = 1.f, p = gh;
    #pragma unroll
    for (int i = 0; i < 6; ++i) { w *= ((e >> i) & 1) ? p : 1.f; p *= p; }
    return w;
}

// ---------------------------------------------------------------------------
// K1 (32 blocks, rescheduled for occupancy): per block, wave 0 runs the
// W-scan + Qb pack for chunk wv = blockIdx (32 W-waves spread over 32 CUs,
// co-resident with 3 Pa-pack waves each for latency hiding — R18 ran all
// W-waves at 1 wave/SIMD on 8 CUs, fully exposing scan/pack latency).
// Waves 1-3: Pa pack, pw = blockIdx*3 + wid-1 (96 slots, 64 used).
// All computation code verbatim R18 (verified).
// ---------------------------------------------------------------------------
extern "C" __global__ __launch_bounds__(256)
void dlm_k1_pack(const float* __restrict__ Xt, const float* __restrict__ Zt,
                 const float* __restrict__ G, const float* __restrict__ eta,
                 const float* __restrict__ zeta, const float* __restrict__ gamma,
                 unsigned short* __restrict__ Pa, unsigned short* __restrict__ Qb)
{
    const int tid  = threadIdx.x;
    const int wid  = tid >> 6;
    const int lane = tid & 63;

    if (wid != 0) {
        // ---------------- Pa pack: 3 waves/block, 96 slots for 64 groups ----
        const int pw = blockIdx.x * 3 + (wid - 1);   // 0..95
        if (pw >= 64) return;
        const int r  = pw * 64 + lane;
        const float4 e0 = *reinterpret_cast<const float4*>(eta   + (size_t)r * 8);
        const float4 e1 = *reinterpret_cast<const float4*>(eta   + (size_t)r * 8 + 4);
        const float4 c0 = *reinterpret_cast<const float4*>(zeta  + (size_t)r * 8);
        const float4 c1 = *reinterpret_cast<const float4*>(zeta  + (size_t)r * 8 + 4);
        const float4 m0 = *reinterpret_cast<const float4*>(gamma + (size_t)r * 8);
        const float4 m1 = *reinterpret_cast<const float4*>(gamma + (size_t)r * 8 + 4);
        const float pr[24] = {e0.x, e0.y, e0.z, e0.w, e1.x, e1.y, e1.z, e1.w,
                              c0.x, c0.y, c0.z, c0.w, c1.x, c1.y, c1.z, c1.w,
                              m0.x, m0.y, m0.z, m0.w, m1.x, m1.y, m1.z, m1.w};
        const int rt = r >> 4, rw = r & 15;
        #pragma unroll
        for (int s = 0; s < NKS; ++s) {
            #pragma unroll
            for (int ko = 0; ko < 4; ++ko) {
                union { unsigned short u[8]; uint4 v; } pk;
                #pragma unroll
                for (int i = 0; i < 8; ++i) {
                    const int k = s * 32 + ko * 8 + i;
                    unsigned short o;
                    if (k < 24)      o = f2bf(pr[k]);
                    else if (k < 48) o = f2bf(pr[k - 24]);
                    else if (k < 72) { const unsigned short h = f2bf(pr[k - 48]);
                                       o = f2bf(pr[k - 48] - bf2f(h)); }
                    else             o = 0;
                    pk.u[i] = o;
                }
                *reinterpret_cast<uint4*>(Pa + ((size_t)((rt * NKS + s) * 4 + ko) * 16 + rw) * 8) = pk.v;
            }
        }
        return;
    }

    // ---------------- W-scan + Qb pack: wave 0, chunk wv = blockIdx ----------
    const int wv = blockIdx.x;             // 0..31
    const int t  = wv * 64 + lane;

    const float gh = sigmoidf_(G[0]);
    float gh64 = gh;
    #pragma unroll
    for (int i = 0; i < 6; ++i) gh64 *= gh64;

    const float4 za = *reinterpret_cast<const float4*>(Zt + (size_t)t * 8);
    const float4 zb = *reinterpret_cast<const float4*>(Zt + (size_t)t * 8 + 4);
    const float4 xa = *reinterpret_cast<const float4*>(Xt + (size_t)t * 8);
    const float4 xb = *reinterpret_cast<const float4*>(Xt + (size_t)t * 8 + 4);

    // ---- W prefix, batched-8 (R18-verified)
    float acc[8] = {0.f, 0.f, 0.f, 0.f, 0.f, 0.f, 0.f, 0.f};
    #pragma unroll
    for (int base = 0; base < 32; base += 8) {
        if (base < wv) {                          // wave-uniform guard
            float4 pa[8], pb[8];
            #pragma unroll
            for (int i = 0; i < 8; ++i) {
                const int mm = (base + i < wv) ? (base + i) : (wv - 1);  // clamped
                const float* __restrict__ zp = Zt + (size_t)(mm * 64 + lane) * 8;
                pa[i] = *reinterpret_cast<const float4*>(zp);
                pb[i] = *reinterpret_cast<const float4*>(zp + 4);
            }
            #pragma unroll
            for (int i = 0; i < 8; ++i) {
                const bool act = (base + i) < wv;
                const float m = act ? gh64 : 1.0f;
                acc[0] = fmaf(m, acc[0], act ? pa[i].x : 0.0f);
                acc[1] = fmaf(m, acc[1], act ? pa[i].y : 0.0f);
                acc[2] = fmaf(m, acc[2], act ? pa[i].z : 0.0f);
                acc[3] = fmaf(m, acc[3], act ? pa[i].w : 0.0f);
                acc[4] = fmaf(m, acc[4], act ? pb[i].x : 0.0f);
                acc[5] = fmaf(m, acc[5], act ? pb[i].y : 0.0f);
                acc[6] = fmaf(m, acc[6], act ? pb[i].z : 0.0f);
                acc[7] = fmaf(m, acc[7], act ? pb[i].w : 0.0f);
            }
        }
    }
    const float wl = powg(gh, 63 - lane);
    #pragma unroll
    for (int i = 0; i < 8; ++i) acc[i] *= wl;
    #pragma unroll
    for (int d = 1; d < 64; d <<= 1) {
        #pragma unroll
        for (int i = 0; i < 8; ++i)
            acc[i] += __shfl_xor(acc[i], d, 64);
    }

    float I[8] = {za.x, za.y, za.z, za.w, zb.x, zb.y, zb.z, zb.w};
    float p = gh;
    #pragma unroll
    for (int d = 1; d < 64; d <<= 1) {
        #pragma unroll
        for (int i = 0; i < 8; ++i) {
            const float up = __shfl_up(I[i], (unsigned)d, 64);
            if (lane >= d) I[i] = fmaf(p, up, I[i]);
        }
        p *= p;
    }

    const float wj = powg(gh, lane);
    float Wt[8];
    #pragma unroll
    for (int i = 0; i < 8; ++i) {
        const float L = __shfl_up(I[i], 1u, 64);
        Wt[i] = fmaf(wj, acc[i], (lane == 0) ? 0.0f : L);
    }

    const float q[24] = {xa.x, xa.y, xa.z, xa.w, xb.x, xb.y, xb.z, xb.w,
                         za.x, za.y, za.z, za.w, zb.x, zb.y, zb.z, zb.w,
                         Wt[0], Wt[1], Wt[2], Wt[3], Wt[4], Wt[5], Wt[6], Wt[7]};
    const int tt = t >> 4, c = t & 15;
    #pragma unroll
    for (int s = 0; s < NKS; ++s) {
        #pragma unroll
        for (int ko = 0; ko < 4; ++ko) {
            union { unsigned short u[8]; uint4 v; } pk;
            #pragma unroll
            for (int i = 0; i < 8; ++i) {
                const int k = s * 32 + ko * 8 + i;
                unsigned short o;
                if (k < 24)      o = f2bf(q[k]);
                else if (k < 48) { const unsigned short h = f2bf(q[k - 24]);
                                   o = f2bf(q[k - 24] - bf2f(h)); }
                else if (k < 72) o = f2bf(q[k - 48]);
                else             o = 0;
                pk.u[i] = o;
            }
            *reinterpret_cast<uint4*>(Qb + ((size_t)((tt * NKS + s) * 4 + ko) * 16 + c) * 8) = pk.v;
        }
    }
}

// ---------------------------------------------------------------------------
// KB — exact R13 version (best measured: 7.8us). wave -> 32x32 output tile
// (2x2 of 16x16 MFMA), 12 dwordx4 frag loads + 12 MFMA + 16 NT dword stores.
// Fallback (wave's G slice not all == G[0]): exact serial replay from t=0.
// ---------------------------------------------------------------------------
extern "C" __global__ __launch_bounds__(256)
void dlm_kb_mfma(const float* __restrict__ Xt, const float* __restrict__ Zt,
                 const float* __restrict__ G, const float* __restrict__ eta,
                 const float* __restrict__ zeta, const float* __restrict__ gamma,
                 const unsigned short* __restrict__ Pa,
                 const unsigned short* __restrict__ Qb,
                 float* __restrict__ out)
{
    const int tid  = threadIdx.x;
    const int wid  = tid >> 6;
    const int lane = tid & 63;
    const int w    = blockIdx.x * 4 + wid;    // 0..8191
    const int rt0  = (w & 127) * 2;
    const int tt0  = (w >> 7) * 2;
    const int r0   = rt0 * 16;
    const int t0   = tt0 * 16;

    const float G0 = G[0];
    const float gv = G[r0 + (lane & 31)];
    const bool uni = (__ballot(gv == G0) == ~0ull);

    if (uni) {
        const int ko = lane >> 4;
        const int rc = lane & 15;

        bf16x8 af[2][NKS], bfr[2][NKS];
        #pragma unroll
        for (int i = 0; i < 2; ++i)
            #pragma unroll
            for (int s = 0; s < NKS; ++s) {
                af[i][s] = *reinterpret_cast<const bf16x8*>(
                    Pa + ((size_t)(((rt0 + i) * NKS + s) * 4 + ko) * 16 + rc) * 8);
                bfr[i][s] = *reinterpret_cast<const bf16x8*>(
                    Qb + ((size_t)(((tt0 + i) * NKS + s) * 4 + ko) * 16 + rc) * 8);
            }

        f32x4 accv[2][2];
        #pragma unroll
        for (int i = 0; i < 2; ++i)
            #pragma unroll
            for (int j = 0; j < 2; ++j)
                accv[i][j] = (f32x4){0.f, 0.f, 0.f, 0.f};

        #pragma unroll
        for (int s = 0; s < NKS; ++s)
            #pragma unroll
            for (int i = 0; i < 2; ++i)
                #pragma unroll
                for (int j = 0; j < 2; ++j)
                    accv[i][j] = __builtin_amdgcn_mfma_f32_16x16x32_bf16(
                        af[i][s], bfr[j][s], accv[i][j], 0, 0, 0);

        const int orow = (lane >> 4) * 4;
        const int ocol = lane & 15;
        #pragma unroll
        for (int i = 0; i < 2; ++i)
            #pragma unroll
            for (int j = 0; j < 2; ++j)
                #pragma unroll
                for (int qv = 0; qv < 4; ++qv)
                    __builtin_nontemporal_store(
                        accv[i][j][qv],
                        &out[(size_t)(r0 + 16 * i + orow + qv) * T_STEPS + t0 + 16 * j + ocol]);
    } else {
        const int t = t0 + (lane & 31);
        const float4 fxa = *reinterpret_cast<const float4*>(Xt + (size_t)t * 8);
        const float4 fxb = *reinterpret_cast<const float4*>(Xt + (size_t)t * 8 + 4);
        const float4 fza = *reinterpret_cast<const float4*>(Zt + (size_t)t * 8);
        const float4 fzb = *reinterpret_cast<const float4*>(Zt + (size_t)t * 8 + 4);
        for (int rr = 0; rr < 32; ++rr) {
            const int r = r0 + rr;
            const float ghr = sigmoidf_(G[r]);
            const float* __restrict__ gc = gamma + (size_t)r * 8;
            const float* __restrict__ e  = eta   + (size_t)r * 8;
            const float* __restrict__ zc = zeta  + (size_t)r * 8;
            float th = 0.0f, mine = 0.0f;
            for (int s2 = 1; s2 <= t0 + 31; ++s2) {
                const float* __restrict__ zr = Zt + (size_t)(s2 - 1) * 8;
                float b = zr[0] * gc[0];
                #pragma unroll
                for (int qq = 1; qq < 8; ++qq) b = fmaf(zr[qq], gc[qq], b);
                th = fmaf(ghr, th, b);
                mine = (s2 == t) ? th : mine;
            }
            float s = mine;
            s = fmaf(fxa.x, e[0], s);  s = fmaf(fxa.y, e[1], s);
            s = fmaf(fxa.z, e[2], s);  s = fmaf(fxa.w, e[3], s);
            s = fmaf(fxb.x, e[4], s);  s = fmaf(fxb.y, e[5], s);
            s = fmaf(fxb.z, e[6], s);  s = fmaf(fxb.w, e[7], s);
            s = fmaf(fza.x, zc[0], s); s = fmaf(fza.y, zc[1], s);
            s = fmaf(fza.z, zc[2], s); s = fmaf(fza.w, zc[3], s);
            s = fmaf(fzb.x, zc[4], s); s = fmaf(fzb.y, zc[5], s);
            s = fmaf(fzb.z, zc[6], s); s = fmaf(fzb.w, zc[7], s);
            if (lane < 32) out[(size_t)r * T_STEPS + t] = s;
        }
    }
}

// ---------------------------------------------------------------------------
extern "C" void kernel_launch(void* const* d_in, const int* in_sizes, int n_in,
                              void* d_out, int out_size, void* d_ws, size_t ws_size,
                              hipStream_t stream)
{
    const float* Xt    = (const float*)d_in[0];
    const float* Zt    = (const float*)d_in[1];
    const float* G     = (const float*)d_in[2];
    const float* eta   = (const float*)d_in[3];
    const float* zeta  = (const float*)d_in[4];
    const float* gamma = (const float*)d_in[5];
    float* out = (float*)d_out;

    unsigned short* Pa = (unsigned short*)d_ws;
    unsigned short* Qb = Pa + PA_ELEMS;

    const dim3 blk(256);
    dlm_k1_pack<<<dim3(32),   blk, 0, stream>>>(Xt, Zt, G, eta, zeta, gamma, Pa, Qb);
    dlm_kb_mfma<<<dim3(2048), blk, 0, stream>>>(Xt, Zt, G, eta, zeta, gamma, Pa, Qb, out);
}